// Round 1
// baseline (156.397 us; speedup 1.0000x reference)
//
#include <hip/hip_runtime.h>

// LSTM B=32768, T=50, I=2, H=32. 512 blocks x 256 threads = 4 independent
// waves/block (R9 shell: private LDS/wave, barrier-free recurrence).
// R13: R12 program with three structural de-scaffolding changes:
//  1. MFMA C-init: ci = W_ih*x + b folded into a 4th MFMA per tile.
//     A = [xh0,xl0,xh1,xl1,xh0,xh1,1,1] (q==0 lanes), B = [wh0,wh0,wh1,wh1,
//     wl0,wl1,bh,bl]; xh*wh+xl*wh = x*wh EXACT in f32 accum, bias split.
//     Replaces pk C-init (64cyc) + quad-scatter movs (~64cyc) + x prefetch
//     with 8 MFMAs (~40cyc) + 1 ds_read_b64 + ~7 VALU.
//  2. Unit remap: tile n covers units 2*u0+(n&1) (gg = gate*32+2*u0+(n&1)),
//     so pk activation pairs are ROW-pairs = adjacent quad elements of acc
//     -> zero movs building f32x2 inputs (was ~64cyc of cross-quad movs).
//  3. Plane-split h: separate bf16-hi / bf16-lo LDS planes; A-frag read is
//     2x ds_read_b128 raw, 0 perms (was 8 perms/t).
// Issue model (calibrated R1/R7-R12): wall ~ 2*issue/0.6; R12 ~1450/wave-t,
// R13 ~1220 (trans 768 unchanged: 40 exp + 8 rcp; MFMA 27->35).
// Core: full M=16 mfma_f32_16x16x32_bf16, split-precision h (hh*Wh+hl*Wh+
// hh*Bl), head = 3 MFMAs vs replicated W_out, scales folded (-log2e/+2log2e),
// clamps on zg and c only (CL=14).

#define TS 50
#define HSTR 20     // u32 stride of each h plane row (80 B): 16B-aligned reads
#define CL 14.0f
#define WPB 4       // waves per block

typedef short short8 __attribute__((ext_vector_type(8)));
typedef float f32x4 __attribute__((ext_vector_type(4)));
typedef float f32x2 __attribute__((ext_vector_type(2)));

__device__ __forceinline__ float fast_exp2(float x) {
    return __builtin_amdgcn_exp2f(x);
}
__device__ __forceinline__ float fast_rcp(float x) {
    return __builtin_amdgcn_rcpf(x);
}
__device__ __forceinline__ f32x2 pexp(f32x2 z) {           // scalar trans x2
    f32x2 r; r.x = fast_exp2(z.x); r.y = fast_exp2(z.y); return r;
}
__device__ __forceinline__ f32x2 prcp(f32x2 v) {           // scalar trans x2
    f32x2 r; r.x = fast_rcp(v.x); r.y = fast_rcp(v.y); return r;
}
__device__ __forceinline__ f32x2 vmin2(f32x2 v, float s) { // -> v_pk_min_f32
    f32x2 r; r.x = fminf(v.x, s); r.y = fminf(v.y, s); return r;
}
// v ~= hi + lo (bf16 each, trunc). returns (lo<<16)|hi
__device__ __forceinline__ unsigned split_pack(float v) {
    unsigned u   = __float_as_uint(v);
    float    res = v - __uint_as_float(u & 0xffff0000u);
    return __builtin_amdgcn_perm(__float_as_uint(res), u, 0x07060302u);
}
// (a & 0xffff) | (b << 16)
__device__ __forceinline__ unsigned lo_pair(unsigned a, unsigned b) {
    return __builtin_amdgcn_perm(b, a, 0x05040100u);
}
// (a >> 16) | (b & 0xffff0000)
__device__ __forceinline__ unsigned hi_pair(unsigned a, unsigned b) {
    return __builtin_amdgcn_perm(b, a, 0x07060302u);
}

union U4S8 { uint4 v; short8 s; unsigned u[4]; };

__global__ __launch_bounds__(256, 2)
void lsnn_kernel(const float* __restrict__ x,
                 const float* __restrict__ W_ih,
                 const float* __restrict__ W_hh,
                 const float* __restrict__ b_ih,
                 const float* __restrict__ b_hh,
                 const float* __restrict__ W_out,
                 const float* __restrict__ b_out,
                 const float* __restrict__ h0,
                 const float* __restrict__ c0,
                 float* __restrict__ out)
{
    __shared__ __align__(16) float    x_lds[WPB][16 * 100];
    __shared__ __align__(16) unsigned hhi[WPB][16 * HSTR];  // bf16-hi plane
    __shared__ __align__(16) unsigned hlo[WPB][16 * HSTR];  // bf16-lo plane
    __shared__ __align__(16) float    out_lds[WPB][16 * TS];

    const int  g_w  = threadIdx.x >> 6;
    const int  lane = threadIdx.x & 63;
    const int  u0   = lane & 15;
    const int  q    = lane >> 4;
    const long b0   = ((long)blockIdx.x * WPB + g_w) * 16;

    float*    xw   = x_lds[g_w];
    unsigned* hh_w = hhi[g_w];
    unsigned* hl_w = hlo[g_w];
    float*    ow   = out_lds[g_w];

    // ---- stage this wave's x: 1600 contiguous floats ----
    {
        const float4* xs = (const float4*)(x + b0 * 100);
        float4* xd = (float4*)xw;
        for (int i = lane; i < 400; i += 64) xd[i] = xs[i];
    }
    // ---- init h planes: word [row][j] = units (2j, 2j+1) ----
    for (int i = lane; i < 256; i += 64) {
        int row = i >> 4, j = i & 15;
        float2 v = *(const float2*)&h0[(b0 + row) * 32 + 2 * j];
        unsigned p0 = split_pack(v.x), p1 = split_pack(v.y);
        hh_w[row * HSTR + j] = lo_pair(p0, p1);   // [hi(v0), hi(v1)]
        hl_w[row * HSTR + j] = hi_pair(p0, p1);   // [lo(v0), lo(v1)]
    }

    const float L2E = 1.4426950408889634f;
    const float SG  = 2.0f * L2E;

    // ---- W_hh B-tiles (8): tile n -> gate n>>1, unit 2*u0+(n&1) ----
    // ---- Bx tiles: ci-MFMA B-frag, rows k=0..7 live only in q==0 lanes ----
    short8 Bh[8], Bl[8], Bx[8];
    #pragma unroll
    for (int n = 0; n < 8; ++n) {
        const float s  = ((n >> 1) == 2) ? SG : -L2E;
        const int   gg = (n >> 1) * 32 + 2 * u0 + (n & 1);
        const float* wr = W_hh + gg * 32 + q * 8;
        U4S8 uh, ul;
        #pragma unroll
        for (int p = 0; p < 4; ++p) {
            unsigned p0 = split_pack(wr[2*p]   * s);
            unsigned p1 = split_pack(wr[2*p+1] * s);
            uh.u[p] = lo_pair(p0, p1);
            ul.u[p] = hi_pair(p0, p1);
        }
        Bh[n] = uh.s;  Bl[n] = ul.s;
        U4S8 ux;
        if (q == 0) {
            unsigned s0 = split_pack(W_ih[gg * 2 + 0] * s);
            unsigned s1 = split_pack(W_ih[gg * 2 + 1] * s);
            unsigned sb = split_pack((b_ih[gg] + b_hh[gg]) * s);
            ux.u[0] = lo_pair(s0, s0);   // [wh0, wh0]
            ux.u[1] = lo_pair(s1, s1);   // [wh1, wh1]
            ux.u[2] = hi_pair(s0, s1);   // [wl0, wl1]
            ux.u[3] = sb;                // [bh,  bl ]
        } else {
            ux.u[0] = 0u; ux.u[1] = 0u; ux.u[2] = 0u; ux.u[3] = 0u;
        }
        Bx[n] = ux.s;
    }
    // ---- head B-frag: B[k][n] = w_out[k] replicated over n ----
    short8 Bwh, Bwl;
    {
        U4S8 uh, ul;
        #pragma unroll
        for (int p = 0; p < 4; ++p) {
            unsigned p0 = split_pack(W_out[q * 8 + 2*p]);
            unsigned p1 = split_pack(W_out[q * 8 + 2*p + 1]);
            uh.u[p] = lo_pair(p0, p1);
            ul.u[p] = hi_pair(p0, p1);
        }
        Bwh = uh.s;  Bwl = ul.s;
    }
    const float bout = b_out[0];

    // ---- c-state groups g = par*2+rr: rows (q*4+2rr, q*4+2rr+1), unit 2u0+par
    f32x2 cst2[4];
    #pragma unroll
    for (int par = 0; par < 2; ++par)
        #pragma unroll
        for (int rr = 0; rr < 2; ++rr) {
            cst2[par*2+rr].x = c0[(b0 + q*4 + 2*rr    ) * 32 + 2*u0 + par];
            cst2[par*2+rr].y = c0[(b0 + q*4 + 2*rr + 1) * 32 + 2*u0 + par];
        }

    const f32x4 ZV = {0.f, 0.f, 0.f, 0.f};
    const int abase = u0 * HSTR + q * 4;

    // ---- x prefetch for t=0 (row u0, broadcast across q) ----
    float2 xp = *(const float2*)&xw[u0 * 100];

    #pragma unroll 1
    for (int t = 0; t < TS; ++t) {
        // ---- A-fragment h_t: row u0, k = q*8..q*8+7 — raw plane reads ----
        U4S8 Ahh, Ahl;
        Ahh.v = *(const uint4*)&hh_w[abase];
        Ahl.v = *(const uint4*)&hl_w[abase];

        // ---- output head for h_t (skip t=0) ----
        if (t > 0) {
            f32x4 aw = ZV;
            aw = __builtin_amdgcn_mfma_f32_16x16x32_bf16(Ahh.s, Bwh, aw, 0, 0, 0);
            aw = __builtin_amdgcn_mfma_f32_16x16x32_bf16(Ahl.s, Bwh, aw, 0, 0, 0);
            aw = __builtin_amdgcn_mfma_f32_16x16x32_bf16(Ahh.s, Bwl, aw, 0, 0, 0);
            if (u0 == 0) {
                #pragma unroll
                for (int r = 0; r < 4; ++r)
                    ow[(q * 4 + r) * TS + (t - 1)] = aw[r] + bout;
            }
        }

        // ---- Ax frag: [xh0, xl0, xh1, xl1, xh0, xh1, 1, 1] ----
        U4S8 Axf;
        {
            unsigned a0 = split_pack(xp.x);
            unsigned a1 = split_pack(xp.y);
            Axf.u[0] = a0;
            Axf.u[1] = a1;
            Axf.u[2] = lo_pair(a0, a1);     // [xh0, xh1]
            Axf.u[3] = 0x3f803f80u;         // [1.0, 1.0] bf16
        }
        if (t + 1 < TS)
            xp = *(const float2*)&xw[u0 * 100 + 2 * (t + 1)];

        // ---- gates: ci-MFMA + 3 split-h MFMAs per tile ----
        f32x4 acc[8];
        #pragma unroll
        for (int n = 0; n < 8; ++n)
            acc[n] = __builtin_amdgcn_mfma_f32_16x16x32_bf16(Axf.s, Bx[n], ZV, 0, 0, 0);
        #pragma unroll
        for (int n = 0; n < 8; ++n) {
            acc[n] = __builtin_amdgcn_mfma_f32_16x16x32_bf16(Ahh.s, Bh[n], acc[n], 0, 0, 0);
            acc[n] = __builtin_amdgcn_mfma_f32_16x16x32_bf16(Ahl.s, Bh[n], acc[n], 0, 0, 0);
            acc[n] = __builtin_amdgcn_mfma_f32_16x16x32_bf16(Ahh.s, Bl[n], acc[n], 0, 0, 0);
        }

        // ---- activations: 4 f32x2 ROW-pair groups (adjacent quad elems) ----
        // tiles: 0,1=i; 2,3=f; 4,5=g; 6,7=o (tile = gate*2 + par)
        f32x2 Bv2[4], Cv2[4], P12[4], Ep2[4], PP2[4];
        #pragma unroll
        for (int par = 0; par < 2; ++par) {
            #pragma unroll
            for (int rr = 0; rr < 2; ++rr) {
                const int g = par * 2 + rr;
                f32x2 zi = {acc[0+par][2*rr], acc[0+par][2*rr+1]};
                f32x2 zf = {acc[2+par][2*rr], acc[2+par][2*rr+1]};
                f32x2 zg = vmin2((f32x2){acc[4+par][2*rr], acc[4+par][2*rr+1]}, CL);
                f32x2 zo = {acc[6+par][2*rr], acc[6+par][2*rr+1]};
                f32x2 Av = pexp(zi);          // e^{-i}
                Bv2[g]   = pexp(zg);          // e^{2g}
                f32x2 Ev = pexp(zf);          // e^{-f}
                Cv2[g]   = pexp(zo);          // e^{-o}
                f32x2 Ap = 1.0f + Av, Bp = 1.0f + Bv2[g];
                Ep2[g] = 1.0f + Ev;
                P12[g] = Ap * Bp;
                PP2[g] = P12[g] * Ep2[g];
            }
        }
        // batch-shared reciprocals across group pairs (0,1) and (2,3)
        f32x2 R2[4];
        #pragma unroll
        for (int bb = 0; bb < 2; ++bb) {
            f32x2 pr = PP2[2*bb] * PP2[2*bb + 1];
            f32x2 ri = prcp(pr);
            R2[2*bb]     = PP2[2*bb + 1] * ri;
            R2[2*bb + 1] = PP2[2*bb]     * ri;
        }
        f32x2 Dv2[4], Q2[4];
        #pragma unroll
        for (int g = 0; g < 4; ++g) {
            f32x2 fv = P12[g] * R2[g];                      // sigmoid(f)
            f32x2 ig = (Bv2[g] - 1.0f) * (Ep2[g] * R2[g]);  // sig(i)*tanh(g)
            f32x2 c  = fv * cst2[g] + ig;
            cst2[g] = c;
            f32x2 zc = vmin2(c * SG, CL);
            Dv2[g] = pexp(zc);                              // e^{2c}
            Q2[g]  = (1.0f + Cv2[g]) * (1.0f + Dv2[g]);
        }
        f32x2 RQ2[4];
        #pragma unroll
        for (int bb = 0; bb < 2; ++bb) {
            f32x2 qr = Q2[2*bb] * Q2[2*bb + 1];
            f32x2 ri = prcp(qr);
            RQ2[2*bb]     = Q2[2*bb + 1] * ri;
            RQ2[2*bb + 1] = Q2[2*bb]     * ri;
        }
        // ---- h store: per row, word = [hi(even unit), hi(odd unit)] ----
        #pragma unroll
        for (int rr = 0; rr < 2; ++rr) {
            f32x2 he = (Dv2[rr]     - 1.0f) * RQ2[rr];      // even unit rows
            f32x2 ho = (Dv2[2 + rr] - 1.0f) * RQ2[2 + rr];  // odd  unit rows
            unsigned hex = __float_as_uint(he.x), hey = __float_as_uint(he.y);
            unsigned hox = __float_as_uint(ho.x), hoy = __float_as_uint(ho.y);
            f32x2 rese, reso;
            rese.x = he.x - __uint_as_float(hex & 0xffff0000u);
            rese.y = he.y - __uint_as_float(hey & 0xffff0000u);
            reso.x = ho.x - __uint_as_float(hox & 0xffff0000u);
            reso.y = ho.y - __uint_as_float(hoy & 0xffff0000u);
            const int row0 = q * 4 + 2 * rr;
            hh_w[ row0      * HSTR + u0] = hi_pair(hex, hox);
            hl_w[ row0      * HSTR + u0] = hi_pair(__float_as_uint(rese.x),
                                                   __float_as_uint(reso.x));
            hh_w[(row0 + 1) * HSTR + u0] = hi_pair(hey, hoy);
            hl_w[(row0 + 1) * HSTR + u0] = hi_pair(__float_as_uint(rese.y),
                                                   __float_as_uint(reso.y));
        }
    }

    // ---- final head for h_50 ----
    {
        U4S8 Ahh, Ahl;
        Ahh.v = *(const uint4*)&hh_w[abase];
        Ahl.v = *(const uint4*)&hl_w[abase];
        f32x4 aw = {0.f, 0.f, 0.f, 0.f};
        aw = __builtin_amdgcn_mfma_f32_16x16x32_bf16(Ahh.s, Bwh, aw, 0, 0, 0);
        aw = __builtin_amdgcn_mfma_f32_16x16x32_bf16(Ahl.s, Bwh, aw, 0, 0, 0);
        aw = __builtin_amdgcn_mfma_f32_16x16x32_bf16(Ahh.s, Bwl, aw, 0, 0, 0);
        if (u0 == 0) {
            #pragma unroll
            for (int r = 0; r < 4; ++r)
                ow[(q * 4 + r) * TS + 49] = aw[r] + bout;
        }
    }

    // ---- coalesced flush of this wave's 800 contiguous floats ----
    {
        float4* od = (float4*)(out + b0 * 50);
        const float4* os = (const float4*)ow;
        for (int i = lane; i < 200; i += 64) od[i] = os[i];
    }
}

extern "C" void kernel_launch(void* const* d_in, const int* in_sizes, int n_in,
                              void* d_out, int out_size, void* d_ws, size_t ws_size,
                              hipStream_t stream) {
    const float* x     = (const float*)d_in[0];
    const float* W_ih  = (const float*)d_in[1];
    const float* W_hh  = (const float*)d_in[2];
    const float* b_ih  = (const float*)d_in[3];
    const float* b_hh  = (const float*)d_in[4];
    const float* W_out = (const float*)d_in[5];
    const float* b_out = (const float*)d_in[6];
    const float* h0    = (const float*)d_in[7];
    const float* c0    = (const float*)d_in[8];
    float* out = (float*)d_out;

    dim3 grid(32768 / (16 * WPB)), block(64 * WPB);
    lsnn_kernel<<<grid, block, 0, stream>>>(x, W_ih, W_hh, b_ih, b_hh,
                                            W_out, b_out, h0, c0, out);
}